// Round 4
// baseline (281.876 us; speedup 1.0000x reference)
//
#include <hip/hip_runtime.h>
#include <cstdint>
#include <cstddef>

typedef float v2f __attribute__((ext_vector_type(2)));

#define HID 16
#define IN  30

#define FAST_RCP(x) __builtin_amdgcn_rcpf(x)

__device__ __forceinline__ float fsig(float x) {
    float e = __expf(-x);
    return FAST_RCP(1.0f + e);
}
__device__ __forceinline__ float ftanh(float x) {
    float e = __expf(2.0f * x);
    return fmaf(-2.0f, FAST_RCP(e + 1.0f), 1.0f);
}
__device__ __forceinline__ float bperm(int baddr, float v) {
    return __int_as_float(__builtin_amdgcn_ds_bpermute(baddr, __float_as_int(v)));
}
// quad_perm [1,0,3,2]: lane ^ 1 exchange, pure VALU (no LDS round-trip)
__device__ __forceinline__ float dppswap1(float v) {
    return __int_as_float(__builtin_amdgcn_mov_dpp(__float_as_int(v), 0xB1, 0xF, 0xF, true));
}
#define PKFMA(acc, a, b) asm("v_pk_fma_f32 %0, %1, %2, %0" : "+v"(acc) : "v"(a), "v"(b))

// ---------------- counting-sort kernels (bins by length, descending) ----------------
__global__ void k_hist(const int* __restrict__ len, int* __restrict__ hist, int B, int T) {
    int i = blockIdx.x * 256 + threadIdx.x;
    if (i < B) atomicAdd(hist + (T - len[i]), 1);
}
__global__ __launch_bounds__(512) void k_scan(const int* __restrict__ hist, int* __restrict__ off) {
    __shared__ int s[512];
    int t = threadIdx.x;
    int v = hist[t];
    s[t] = v; __syncthreads();
    int acc = v;
    for (int o = 1; o < 512; o <<= 1) {
        int add = (t >= o) ? s[t - o] : 0;
        __syncthreads();
        acc += add; s[t] = acc;
        __syncthreads();
    }
    off[t] = acc - v;   // exclusive prefix
}
__global__ void k_scatter(const int* __restrict__ len, int* __restrict__ off,
                          int* __restrict__ perm, int B, int T) {
    int i = blockIdx.x * 256 + threadIdx.x;
    if (i < B) {
        int b = T - len[i];
        int p = atomicAdd(off + b, 1);
        perm[p] = i;
    }
}

// ---------------- main GRU kernel: 8 waves/block, 2 rows/wave ----------------
__global__ __launch_bounds__(512, 2) void gru_enc_kernel(
    const float* __restrict__ x, const int* __restrict__ lengths,
    const float* __restrict__ w_ih, const float* __restrict__ w_hh,
    const float* __restrict__ b_ih, const float* __restrict__ b_hh,
    const float* __restrict__ fc1w, const float* __restrict__ fc1b,
    const float* __restrict__ fc2w, const float* __restrict__ fc2b,
    const float* __restrict__ fc3w, const float* __restrict__ fc3b,
    float* __restrict__ out, const int* __restrict__ perm,
    int B, int T, int NP)
{
    const int lane = threadIdx.x & 63;
    const int wib  = threadIdx.x >> 6;        // wave in block, 0..7
    const int rb   = lane & 32;               // row-group bit
    const int half = lane & 1;                // k-dimension half (DPP-adjacent)
    const int j    = (lane >> 1) & 15;        // hidden index owned

    // block-uniform lengths: block b handles sorted pairs 8b..8b+7, so the two
    // waves sharing each SIMD have ~equal length and stay co-resident (2-way
    // latency hiding for the whole block lifetime)
    const int pos = blockIdx.x * 8 + wib;
    if (pos >= NP) return;

    int ridx = 2 * pos + (rb >> 5);
    if (ridx >= B) ridx = B - 1;
    const int row = perm ? perm[ridx] : ridx;

    const int len = lengths[row];
    const int maxlen = max(len, __shfl_xor(len, 32));

    // ---- per-lane weights ----
    // input: half0 covers k=0..14 (window 0..15, p15 zeroed);
    //        half1 covers k=15..29 (window 14..29, p0 zeroed)
    v2f wih2[3][8];
#pragma unroll
    for (int g = 0; g < 3; ++g) {
        const float* wr = w_ih + (size_t)(g * HID + j) * IN;
#pragma unroll
        for (int m = 0; m < 8; ++m) {
            int p0 = 2 * m, p1 = 2 * m + 1;
            v2f t;
            if (half) { t.x = (p0 == 0) ? 0.0f : wr[14 + p0]; t.y = wr[14 + p1]; }
            else      { t.x = wr[p0]; t.y = (p1 == 15) ? 0.0f : wr[p1]; }
            wih2[g][m] = t;
        }
    }
    v2f whh2[3][4];
#pragma unroll
    for (int g = 0; g < 3; ++g)
#pragma unroll
        for (int m = 0; m < 4; ++m) {
            const float* wr = w_hh + (size_t)(g * HID + j) * HID + half * 8 + 2 * m;
            v2f t; t.x = wr[0]; t.y = wr[1];
            whh2[g][m] = t;
        }

    // biases folded into half-0 accumulator inits (appear once after DPP reduce)
    v2f initR; initR.x = half ? 0.0f : (b_ih[j] + b_hh[j]);               initR.y = 0.0f;
    v2f initZ; initZ.x = half ? 0.0f : (b_ih[HID + j] + b_hh[HID + j]);   initZ.y = 0.0f;
    v2f initN; initN.x = half ? 0.0f : b_ih[2 * HID + j];                 initN.y = 0.0f;
    v2f initH; initH.x = half ? 0.0f : b_hh[2 * HID + j];                 initH.y = 0.0f;

    const float* xr = x + (size_t)row * T * IN + (half ? 14 : 0);

    // bpermute byte addresses for h broadcast: lane needs h_k, k = half*8 + m;
    // source lane = rb | (k<<1)
    int ba0[4], ba1[4];
#pragma unroll
    for (int m = 0; m < 4; ++m) {
        int k0 = half * 8 + 2 * m;
        ba0[m] = (rb | (k0 << 1)) << 2;
        ba1[m] = (rb | ((k0 + 1) << 1)) << 2;
    }

#define LOADX(buf, tt) do {                                        \
        const v2f* p_ = (const v2f*)(xr + (size_t)(tt) * IN);      \
        _Pragma("unroll")                                          \
        for (int m_ = 0; m_ < 8; ++m_) buf[m_] = p_[m_];           \
    } while (0)

#define STEP(t, xv) do {                                                    \
        v2f ar = initR, az = initZ, an = initN, hn = initH;                 \
        _Pragma("unroll")                                                   \
        for (int m_ = 0; m_ < 8; ++m_) {                                    \
            PKFMA(ar, wih2[0][m_], xv[m_]);                                 \
            PKFMA(az, wih2[1][m_], xv[m_]);                                 \
            PKFMA(an, wih2[2][m_], xv[m_]);                                 \
        }                                                                   \
        _Pragma("unroll")                                                   \
        for (int m_ = 0; m_ < 4; ++m_) {                                    \
            PKFMA(ar, whh2[0][m_], hb2[m_]);                                \
            PKFMA(az, whh2[1][m_], hb2[m_]);                                \
            PKFMA(hn, whh2[2][m_], hb2[m_]);                                \
        }                                                                   \
        float pr  = ar.x + ar.y;  pr  += dppswap1(pr);                      \
        float pz  = az.x + az.y;  pz  += dppswap1(pz);                      \
        float pxn = an.x + an.y;  pxn += dppswap1(pxn);                     \
        float phn = hn.x + hn.y;  phn += dppswap1(phn);                     \
        float rg = fsig(pr);                                                \
        float zg = fsig(pz);                                                \
        float ng = ftanh(fmaf(rg, phn, pxn));                               \
        float hnew = fmaf(zg, h_own - ng, ng);                              \
        last  = ((t) == len - 1) ? hnew : last;                             \
        h_own = hnew;                                                       \
        _Pragma("unroll")                                                   \
        for (int m_ = 0; m_ < 4; ++m_) {                                    \
            hb2[m_].x = bperm(ba0[m_], hnew);                               \
            hb2[m_].y = bperm(ba1[m_], hnew);                               \
        }                                                                   \
    } while (0)

    v2f hb2[4];
#pragma unroll
    for (int m = 0; m < 4; ++m) { hb2[m].x = 0.0f; hb2[m].y = 0.0f; }
    float h_own = 0.0f, last = 0.0f;

    // 4-deep x prefetch ring: loads for step t are issued at step t-4, i.e.
    // ~4 * ~240cyc ahead -> covers ~900cyc HBM-miss latency
    const int tcap = T - 1;
    v2f xa[8], xb[8], xc[8], xd[8];
    LOADX(xa, 0);
    LOADX(xb, min(1, tcap));
    LOADX(xc, min(2, tcap));
    LOADX(xd, min(3, tcap));

    for (int t = 0; t < maxlen; t += 4) {
        STEP(t, xa);     LOADX(xa, min(t + 4, tcap));
        STEP(t + 1, xb); LOADX(xb, min(t + 5, tcap));
        STEP(t + 2, xc); LOADX(xc, min(t + 6, tcap));
        STEP(t + 3, xd); LOADX(xd, min(t + 7, tcap));
    }

    // ---- FC head (redundant across halves; cheap, once per row) ----
    float hv[16];
#pragma unroll
    for (int k = 0; k < 16; ++k) hv[k] = __shfl(last, rb + 2 * k, 64);

    float e1 = fc1b[j];
#pragma unroll
    for (int k = 0; k < 16; ++k) e1 = fmaf(fc1w[j * HID + k], hv[k], e1);

    float v1[16];
#pragma unroll
    for (int k = 0; k < 16; ++k) v1[k] = fmaxf(__shfl(e1, rb + 2 * k, 64), 0.0f);

    float e2 = fc2b[j];
#pragma unroll
    for (int k = 0; k < 16; ++k) e2 = fmaf(fc2w[j * HID + k], v1[k], e2);

    float v2a[16];
#pragma unroll
    for (int k = 0; k < 16; ++k) v2a[k] = fmaxf(__shfl(e2, rb + 2 * k, 64), 0.0f);

    float e3 = fc3b[j];
#pragma unroll
    for (int k = 0; k < 16; ++k) e3 = fmaf(fc3w[j * HID + k], v2a[k], e3);

    if (half == 0) out[(size_t)row * HID + j] = e3;
}

extern "C" void kernel_launch(void* const* d_in, const int* in_sizes, int n_in,
                              void* d_out, int out_size, void* d_ws, size_t ws_size,
                              hipStream_t stream) {
    const float* x    = (const float*)d_in[0];
    const int*   lens = (const int*)d_in[1];
    const float* w_ih = (const float*)d_in[2];
    const float* w_hh = (const float*)d_in[3];
    const float* b_ih = (const float*)d_in[4];
    const float* b_hh = (const float*)d_in[5];
    const float* fc1w = (const float*)d_in[6];
    const float* fc1b = (const float*)d_in[7];
    const float* fc2w = (const float*)d_in[8];
    const float* fc2b = (const float*)d_in[9];
    const float* fc3w = (const float*)d_in[10];
    const float* fc3b = (const float*)d_in[11];
    float* out = (float*)d_out;

    const int B = in_sizes[1];
    const int T = (int)(in_sizes[0] / ((size_t)B * IN));

    // ws layout (ints): perm[B] | hist[512] | off[512]
    int* wsI = (int*)d_ws;
    const size_t need = ((size_t)B + 1024) * sizeof(int);
    const bool dosort = (ws_size >= need) && (T <= 512) && (T >= 1);
    int* perm = dosort ? wsI : nullptr;
    int* hist = wsI + B;
    int* off  = wsI + B + 512;

    if (dosort) {
        hipMemsetAsync(hist, 0, 512 * sizeof(int), stream);
        k_hist<<<(B + 255) / 256, 256, 0, stream>>>(lens, hist, B, T);
        k_scan<<<1, 512, 0, stream>>>(hist, off);
        k_scatter<<<(B + 255) / 256, 256, 0, stream>>>(lens, off, perm, B, T);
    }

    const int NP   = (B + 1) / 2;
    const int nblk = (NP + 7) / 8;
    gru_enc_kernel<<<nblk, 512, 0, stream>>>(x, lens, w_ih, w_hh, b_ih, b_hh,
                                             fc1w, fc1b, fc2w, fc2b, fc3w, fc3b,
                                             out, perm, B, T, NP);
}

// Round 5
// 171.449 us; speedup vs baseline: 1.6441x; 1.6441x over previous
//
#include <hip/hip_runtime.h>
#include <cstdint>
#include <cstddef>

typedef float v2f __attribute__((ext_vector_type(2)));

#define HID 16
#define IN  30

#define FAST_RCP(x) __builtin_amdgcn_rcpf(x)

__device__ __forceinline__ float bperm(int baddr, float v) {
    return __int_as_float(__builtin_amdgcn_ds_bpermute(baddr, __float_as_int(v)));
}
// quad_perm [1,0,3,2]: lane ^ 1 exchange, pure VALU (no LDS round-trip)
__device__ __forceinline__ float dppswap1(float v) {
    return __int_as_float(__builtin_amdgcn_mov_dpp(__float_as_int(v), 0xB1, 0xF, 0xF, true));
}
#define PKFMA(acc, a, b) asm("v_pk_fma_f32 %0, %1, %2, %0" : "+v"(acc) : "v"(a), "v"(b))

// global -> LDS direct (no VGPR round-trip); dest = wave-uniform base + lane*4
typedef __attribute__((address_space(3))) unsigned int       lds_u32_t;
typedef const __attribute__((address_space(1))) unsigned int glb_u32_t;
#define GLOAD_LDS(gp, lp) \
    __builtin_amdgcn_global_load_lds((glb_u32_t*)(gp), (lds_u32_t*)(lp), 4, 0, 0)

// ---------------- counting-sort kernels (bins by length, descending) ----------------
__global__ void k_hist(const int* __restrict__ len, int* __restrict__ hist, int B, int T) {
    int i = blockIdx.x * 256 + threadIdx.x;
    if (i < B) atomicAdd(hist + (T - len[i]), 1);
}
__global__ __launch_bounds__(512) void k_scan(const int* __restrict__ hist, int* __restrict__ off) {
    __shared__ int s[512];
    int t = threadIdx.x;
    int v = hist[t];
    s[t] = v; __syncthreads();
    int acc = v;
    for (int o = 1; o < 512; o <<= 1) {
        int add = (t >= o) ? s[t - o] : 0;
        __syncthreads();
        acc += add; s[t] = acc;
        __syncthreads();
    }
    off[t] = acc - v;   // exclusive prefix
}
__global__ void k_scatter(const int* __restrict__ len, int* __restrict__ off,
                          int* __restrict__ perm, int B, int T) {
    int i = blockIdx.x * 256 + threadIdx.x;
    if (i < B) {
        int b = T - len[i];
        int p = atomicAdd(off + b, 1);
        perm[p] = i;
    }
}

// ---------------- main GRU kernel: 8 waves/block, 2 rows/wave ----------------
__global__ __launch_bounds__(512, 2) void gru_enc_kernel(
    const float* __restrict__ x, const int* __restrict__ lengths,
    const float* __restrict__ w_ih, const float* __restrict__ w_hh,
    const float* __restrict__ b_ih, const float* __restrict__ b_hh,
    const float* __restrict__ fc1w, const float* __restrict__ fc1b,
    const float* __restrict__ fc2w, const float* __restrict__ fc2b,
    const float* __restrict__ fc3w, const float* __restrict__ fc3b,
    float* __restrict__ out, const int* __restrict__ perm,
    int B, int T, int NP, int nblk)
{
    // per-wave private x staging: 4 buffers x 8 steps x 64 floats (2 rows x 32)
    __shared__ __align__(16) float lds[8][4][8][64];   // 64 KiB

    const int lane = threadIdx.x & 63;
    const int wib  = threadIdx.x >> 6;        // wave in block, 0..7
    const int rb   = lane & 32;               // row-group bit
    const int half = lane & 1;                // k-dimension half (DPP-adjacent)
    const int j    = (lane >> 1) & 15;        // hidden index owned

    // complementary schedule (round-3): waves 0-3 long pairs from front,
    // waves 4-7 short pairs from back; waves i,i+4 share a SIMD -> desynced
    int pos;
    if (wib < 4) pos = 4 * blockIdx.x + wib;
    else         pos = NP - 1 - (4 * blockIdx.x + (wib - 4));
    if (pos < 0 || pos >= NP) return;
    if (wib >= 4 && pos < 4 * nblk) return;   // overlap guard for ragged NP

    int ridx = 2 * pos + (rb >> 5);
    if (ridx >= B) ridx = B - 1;
    const int row = perm ? perm[ridx] : ridx;

    const int len = lengths[row];
    const int maxlen = max(len, __shfl_xor(len, 32));

    const float L2E = 1.4426950408889634f;    // log2(e)

    // ---- per-lane weights, pre-scaled into exp2 domain ----
    // r,z gates: scale by -log2e  (sigmoid(x) = rcp(1 + exp2(-l2e*x)))
    // n gate:    scale by 2*log2e (tanh(y)    = 1 - 2*rcp(exp2(2*l2e*y)+1))
    const float gsc[3] = { -L2E, -L2E, 2.0f * L2E };

    // input: half0 covers k=0..14 (window 0..15, p15 zeroed);
    //        half1 covers k=15..29 (window 14..29, p0 zeroed)
    v2f wih2[3][8];
#pragma unroll
    for (int g = 0; g < 3; ++g) {
        const float* wr = w_ih + (size_t)(g * HID + j) * IN;
#pragma unroll
        for (int m = 0; m < 8; ++m) {
            int p0 = 2 * m, p1 = 2 * m + 1;
            v2f t;
            if (half) { t.x = (p0 == 0) ? 0.0f : wr[14 + p0]; t.y = wr[14 + p1]; }
            else      { t.x = wr[p0]; t.y = (p1 == 15) ? 0.0f : wr[p1]; }
            t.x *= gsc[g]; t.y *= gsc[g];
            wih2[g][m] = t;
        }
    }
    v2f whh2[3][4];
#pragma unroll
    for (int g = 0; g < 3; ++g)
#pragma unroll
        for (int m = 0; m < 4; ++m) {
            const float* wr = w_hh + (size_t)(g * HID + j) * HID + half * 8 + 2 * m;
            v2f t; t.x = wr[0] * gsc[g]; t.y = wr[1] * gsc[g];
            whh2[g][m] = t;
        }

    // biases folded into half-0 accumulator inits (appear once after DPP reduce)
    v2f initR; initR.x = half ? 0.0f : -L2E * (b_ih[j] + b_hh[j]);                 initR.y = 0.0f;
    v2f initZ; initZ.x = half ? 0.0f : -L2E * (b_ih[HID + j] + b_hh[HID + j]);     initZ.y = 0.0f;
    v2f initN; initN.x = half ? 0.0f : 2.0f * L2E * b_ih[2 * HID + j];             initN.y = 0.0f;
    v2f initH; initH.x = half ? 0.0f : 2.0f * L2E * b_hh[2 * HID + j];             initH.y = 0.0f;

    // staging source: this lane's row, word k = lane&31 (clamped 29 for pad)
    const int kk = min(lane & 31, 29);
    const float* xg = x + (size_t)row * T * IN + kk;

    // wave-uniform LDS base for staging; per-lane read base
    float* ldsw = &lds[wib][0][0][0];
    const float* ldsr = ldsw + (rb ? 32 : 0) + half * 14;

    // bpermute byte addresses for h broadcast: lane needs h_k, k = half*8 + m;
    // source lane = rb | (k<<1)
    int ba0[4], ba1[4];
#pragma unroll
    for (int m = 0; m < 4; ++m) {
        int k0 = half * 8 + 2 * m;
        ba0[m] = (rb | (k0 << 1)) << 2;
        ba1[m] = (rb | ((k0 + 1) << 1)) << 2;
    }

    const int tcap = T - 1;

    // stage chunk cc: 8 x global_load_lds (one per step); per-step clamp keeps
    // reads in-bounds; clamped slots are never read by compute
#define STAGE(cc) do {                                                     \
        const int t0_ = (cc) << 3;                                         \
        float* lb_ = ldsw + (((cc) & 3) << 9);                             \
        _Pragma("unroll")                                                  \
        for (int s_ = 0; s_ < 8; ++s_) {                                   \
            int ts_ = min(t0_ + s_, tcap);                                 \
            GLOAD_LDS(xg + (size_t)ts_ * IN, lb_ + (s_ << 6));             \
        }                                                                  \
    } while (0)

#define STEP(t, cw, s) do {                                                 \
        v2f ar = initR, az = initZ, an = initN, hn = initH;                 \
        v2f xv[8];                                                          \
        _Pragma("unroll")                                                   \
        for (int m_ = 0; m_ < 8; ++m_)                                      \
            xv[m_] = *(const v2f*)((cw) + ((s) << 6) + (m_ << 1));          \
        _Pragma("unroll")                                                   \
        for (int m_ = 0; m_ < 8; ++m_) {                                    \
            PKFMA(ar, wih2[0][m_], xv[m_]);                                 \
            PKFMA(az, wih2[1][m_], xv[m_]);                                 \
            PKFMA(an, wih2[2][m_], xv[m_]);                                 \
        }                                                                   \
        _Pragma("unroll")                                                   \
        for (int m_ = 0; m_ < 4; ++m_) {                                    \
            PKFMA(ar, whh2[0][m_], hb2[m_]);                                \
            PKFMA(az, whh2[1][m_], hb2[m_]);                                \
            PKFMA(hn, whh2[2][m_], hb2[m_]);                                \
        }                                                                   \
        float pr  = ar.x + ar.y;  pr  += dppswap1(pr);                      \
        float pz  = az.x + az.y;  pz  += dppswap1(pz);                      \
        float pxn = an.x + an.y;  pxn += dppswap1(pxn);                     \
        float phn = hn.x + hn.y;  phn += dppswap1(phn);                     \
        float rg = FAST_RCP(1.0f + __builtin_exp2f(pr));                    \
        float zg = FAST_RCP(1.0f + __builtin_exp2f(pz));                    \
        float yy = fmaf(rg, phn, pxn);                                      \
        float ng = fmaf(-2.0f, FAST_RCP(1.0f + __builtin_exp2f(yy)), 1.0f); \
        float hnew = fmaf(zg, h_own - ng, ng);                              \
        last  = ((t) == len - 1) ? hnew : last;                             \
        h_own = hnew;                                                       \
        _Pragma("unroll")                                                   \
        for (int m_ = 0; m_ < 4; ++m_) {                                    \
            hb2[m_].x = bperm(ba0[m_], hnew);                               \
            hb2[m_].y = bperm(ba1[m_], hnew);                               \
        }                                                                   \
    } while (0)

    v2f hb2[4];
#pragma unroll
    for (int m = 0; m < 4; ++m) { hb2[m].x = 0.0f; hb2[m].y = 0.0f; }
    float h_own = 0.0f, last = 0.0f;

    const int nch = (maxlen + 7) >> 3;

    // prologue: 3 chunks in flight (24 steps ahead of compute)
    STAGE(0); STAGE(1); STAGE(2);

    for (int c = 0; c < nch; ++c) {
        // chunk c complete when <=16 staging loads outstanding (c+1, c+2)
        asm volatile("s_waitcnt vmcnt(16)" ::: "memory");
        STAGE(c + 3);
        const float* cw = ldsr + ((c & 3) << 9);
        const int nst = min(8, maxlen - (c << 3));
        const int tb = c << 3;
#pragma unroll
        for (int s = 0; s < 8; ++s) {
            if (s >= nst) break;
            STEP(tb + s, cw, s);
        }
    }

    // ---- FC head (redundant across halves; cheap, once per row) ----
    float hv[16];
#pragma unroll
    for (int k = 0; k < 16; ++k) hv[k] = __shfl(last, rb + 2 * k, 64);

    float e1 = fc1b[j];
#pragma unroll
    for (int k = 0; k < 16; ++k) e1 = fmaf(fc1w[j * HID + k], hv[k], e1);

    float v1[16];
#pragma unroll
    for (int k = 0; k < 16; ++k) v1[k] = fmaxf(__shfl(e1, rb + 2 * k, 64), 0.0f);

    float e2 = fc2b[j];
#pragma unroll
    for (int k = 0; k < 16; ++k) e2 = fmaf(fc2w[j * HID + k], v1[k], e2);

    float v2a[16];
#pragma unroll
    for (int k = 0; k < 16; ++k) v2a[k] = fmaxf(__shfl(e2, rb + 2 * k, 64), 0.0f);

    float e3 = fc3b[j];
#pragma unroll
    for (int k = 0; k < 16; ++k) e3 = fmaf(fc3w[j * HID + k], v2a[k], e3);

    if (half == 0) out[(size_t)row * HID + j] = e3;
}

extern "C" void kernel_launch(void* const* d_in, const int* in_sizes, int n_in,
                              void* d_out, int out_size, void* d_ws, size_t ws_size,
                              hipStream_t stream) {
    const float* x    = (const float*)d_in[0];
    const int*   lens = (const int*)d_in[1];
    const float* w_ih = (const float*)d_in[2];
    const float* w_hh = (const float*)d_in[3];
    const float* b_ih = (const float*)d_in[4];
    const float* b_hh = (const float*)d_in[5];
    const float* fc1w = (const float*)d_in[6];
    const float* fc1b = (const float*)d_in[7];
    const float* fc2w = (const float*)d_in[8];
    const float* fc2b = (const float*)d_in[9];
    const float* fc3w = (const float*)d_in[10];
    const float* fc3b = (const float*)d_in[11];
    float* out = (float*)d_out;

    const int B = in_sizes[1];
    const int T = (int)(in_sizes[0] / ((size_t)B * IN));

    // ws layout (ints): perm[B] | hist[512] | off[512]
    int* wsI = (int*)d_ws;
    const size_t need = ((size_t)B + 1024) * sizeof(int);
    const bool dosort = (ws_size >= need) && (T <= 512) && (T >= 8);
    int* perm = dosort ? wsI : nullptr;
    int* hist = wsI + B;
    int* off  = wsI + B + 512;

    if (dosort) {
        hipMemsetAsync(hist, 0, 512 * sizeof(int), stream);
        k_hist<<<(B + 255) / 256, 256, 0, stream>>>(lens, hist, B, T);
        k_scan<<<1, 512, 0, stream>>>(hist, off);
        k_scatter<<<(B + 255) / 256, 256, 0, stream>>>(lens, off, perm, B, T);
    }

    const int NP   = (B + 1) / 2;
    const int nblk = (NP + 7) / 8;
    gru_enc_kernel<<<nblk, 512, 0, stream>>>(x, lens, w_ih, w_hh, b_ih, b_hh,
                                             fc1w, fc1b, fc2w, fc2b, fc3w, fc3b,
                                             out, perm, B, T, NP, nblk);
}

// Round 6
// 167.492 us; speedup vs baseline: 1.6829x; 1.0236x over previous
//
#include <hip/hip_runtime.h>
#include <cstdint>
#include <cstddef>

typedef float v2f __attribute__((ext_vector_type(2)));

#define HID 16
#define IN  30

#define FAST_RCP(x) __builtin_amdgcn_rcpf(x)

__device__ __forceinline__ float bperm(int baddr, float v) {
    return __int_as_float(__builtin_amdgcn_ds_bpermute(baddr, __float_as_int(v)));
}
// quad_perm [1,0,3,2] (lane^1) and [2,3,0,1] (lane^2): pure-VALU quad butterfly
__device__ __forceinline__ float dq1(float v) {
    return __int_as_float(__builtin_amdgcn_mov_dpp(__float_as_int(v), 0xB1, 0xF, 0xF, true));
}
__device__ __forceinline__ float dq2(float v) {
    return __int_as_float(__builtin_amdgcn_mov_dpp(__float_as_int(v), 0x4E, 0xF, 0xF, true));
}
#define PKFMA(acc, a, b) asm("v_pk_fma_f32 %0, %1, %2, %0" : "+v"(acc) : "v"(a), "v"(b))

// global -> LDS direct (no VGPR round-trip); dest = wave-uniform base + lane*4
typedef __attribute__((address_space(3))) unsigned int       lds_u32_t;
typedef const __attribute__((address_space(1))) unsigned int glb_u32_t;
#define GLOAD_LDS(gp, lp) \
    __builtin_amdgcn_global_load_lds((glb_u32_t*)(gp), (lds_u32_t*)(lp), 4, 0, 0)

// ---------------- counting-sort kernels (bins by length, descending) ----------------
__global__ void k_hist(const int* __restrict__ len, int* __restrict__ hist, int B, int T) {
    int i = blockIdx.x * 256 + threadIdx.x;
    if (i < B) atomicAdd(hist + (T - len[i]), 1);
}
__global__ __launch_bounds__(512) void k_scan(const int* __restrict__ hist, int* __restrict__ off) {
    __shared__ int s[512];
    int t = threadIdx.x;
    int v = hist[t];
    s[t] = v; __syncthreads();
    int acc = v;
    for (int o = 1; o < 512; o <<= 1) {
        int add = (t >= o) ? s[t - o] : 0;
        __syncthreads();
        acc += add; s[t] = acc;
        __syncthreads();
    }
    off[t] = acc - v;   // exclusive prefix
}
__global__ void k_scatter(const int* __restrict__ len, int* __restrict__ off,
                          int* __restrict__ perm, int B, int T) {
    int i = blockIdx.x * 256 + threadIdx.x;
    if (i < B) {
        int b = T - len[i];
        int p = atomicAdd(off + b, 1);
        perm[p] = i;
    }
}

// ---------------- main GRU kernel: 8 waves/block, 1 row/wave ----------------
// lane = (j<<2)|q : j = hidden index (16), q = k-quarter (4)
__global__ __launch_bounds__(512, 4) void gru_enc_kernel(
    const float* __restrict__ x, const int* __restrict__ lengths,
    const float* __restrict__ w_ih, const float* __restrict__ w_hh,
    const float* __restrict__ b_ih, const float* __restrict__ b_hh,
    const float* __restrict__ fc1w, const float* __restrict__ fc1b,
    const float* __restrict__ fc2w, const float* __restrict__ fc2b,
    const float* __restrict__ fc3w, const float* __restrict__ fc3b,
    float* __restrict__ out, const int* __restrict__ perm,
    int B, int T, int nblk)
{
    // per-wave private x staging: 4 buffers x 8 steps x 32 floats = 4 KiB/wave
    __shared__ __align__(16) float lds[8][1024];   // 32 KiB/block

    const int lane = threadIdx.x & 63;
    const int wib  = threadIdx.x >> 6;    // wave in block, 0..7
    const int q    = lane & 3;            // k-quarter (DPP quad dimension)
    const int j    = lane >> 2;           // hidden index owned

    // complementary schedule: waves 0-3 long rows from front of sorted order,
    // waves 4-7 short rows from back; waves i,i+4 share a SIMD; block totals equal
    int pos;
    if (wib < 4) pos = 4 * blockIdx.x + wib;
    else         pos = B - 1 - (4 * blockIdx.x + (wib - 4));
    if (pos < 0 || pos >= B) return;
    if (wib >= 4 && pos < 4 * nblk) return;   // overlap guard for ragged B

    const int row = perm ? perm[pos] : pos;
    const int len = lengths[row];             // wave-uniform: exactly len steps

    const float L2E = 1.4426950408889634f;
    // exp2-domain pre-scaling: r,z by -log2e; n by 2*log2e
    const float gsc[3] = { -L2E, -L2E, 2.0f * L2E };

    // ---- per-lane weights ----
    // input slice: k = q*8 .. q*8+7 (k>=30 zeroed)
    v2f wih2[3][4];
#pragma unroll
    for (int g = 0; g < 3; ++g) {
        const float* wr = w_ih + (size_t)(g * HID + j) * IN;
#pragma unroll
        for (int m = 0; m < 4; ++m) {
            int p0 = q * 8 + 2 * m;
            v2f t;
            t.x = (p0     < IN) ? wr[p0]     * gsc[g] : 0.0f;
            t.y = (p0 + 1 < IN) ? wr[p0 + 1] * gsc[g] : 0.0f;
            wih2[g][m] = t;
        }
    }
    // hidden slice: k = q*4 .. q*4+3
    v2f whh2[3][2];
#pragma unroll
    for (int g = 0; g < 3; ++g)
#pragma unroll
        for (int m = 0; m < 2; ++m) {
            const float* wr = w_hh + (size_t)(g * HID + j) * HID + q * 4 + 2 * m;
            v2f t; t.x = wr[0] * gsc[g]; t.y = wr[1] * gsc[g];
            whh2[g][m] = t;
        }

    // biases folded into q==0 lane's accumulator init (counted once in quad reduce)
    v2f initR; initR.x = q ? 0.0f : -L2E * (b_ih[j] + b_hh[j]);               initR.y = 0.0f;
    v2f initZ; initZ.x = q ? 0.0f : -L2E * (b_ih[HID + j] + b_hh[HID + j]);   initZ.y = 0.0f;
    v2f initN; initN.x = q ? 0.0f : 2.0f * L2E * b_ih[2 * HID + j];           initN.y = 0.0f;
    v2f initH; initH.x = q ? 0.0f : 2.0f * L2E * b_hh[2 * HID + j];           initH.y = 0.0f;

    // staging source: word k = min(lane&31,29) of step (lane>>5); 64 lanes = 2 steps
    const int word  = min(lane & 31, 29);
    const int sstep = lane >> 5;
    const float* xrow = x + (size_t)row * T * IN;
    const int tcap = T - 1;

    float* ldsw = &lds[wib][0];
    const float* ldsr = ldsw + q * 8;

    // bpermute byte addresses: lane needs h_k, k = q*4+m; src lane = 4k
    int ba[4];
#pragma unroll
    for (int m = 0; m < 4; ++m) ba[m] = (16 * q + 4 * m) << 2;

    // stage chunk cc (8 steps x 32 words): 4 wide loads, 2 steps each
#define STAGE(cc) do {                                                     \
        const int t0_ = (cc) << 3;                                         \
        float* lb_ = ldsw + (((cc) & 3) << 8);                             \
        _Pragma("unroll")                                                  \
        for (int i_ = 0; i_ < 4; ++i_) {                                   \
            int ts_ = min(t0_ + (i_ << 1) + sstep, tcap);                  \
            GLOAD_LDS(xrow + (size_t)ts_ * IN + word, lb_ + (i_ << 6));    \
        }                                                                  \
    } while (0)

#define STEP(cw, s) do {                                                    \
        float4 xa_ = *(const float4*)((cw) + ((s) << 5));                   \
        float4 xb_ = *(const float4*)((cw) + ((s) << 5) + 4);               \
        v2f xv[4];                                                          \
        xv[0].x = xa_.x; xv[0].y = xa_.y; xv[1].x = xa_.z; xv[1].y = xa_.w; \
        xv[2].x = xb_.x; xv[2].y = xb_.y; xv[3].x = xb_.z; xv[3].y = xb_.w; \
        v2f ar = initR, az = initZ, an = initN, hn = initH;                 \
        _Pragma("unroll")                                                   \
        for (int m_ = 0; m_ < 4; ++m_) {                                    \
            PKFMA(ar, wih2[0][m_], xv[m_]);                                 \
            PKFMA(az, wih2[1][m_], xv[m_]);                                 \
            PKFMA(an, wih2[2][m_], xv[m_]);                                 \
        }                                                                   \
        _Pragma("unroll")                                                   \
        for (int m_ = 0; m_ < 2; ++m_) {                                    \
            PKFMA(ar, whh2[0][m_], hb2[m_]);                                \
            PKFMA(az, whh2[1][m_], hb2[m_]);                                \
            PKFMA(hn, whh2[2][m_], hb2[m_]);                                \
        }                                                                   \
        float pr  = ar.x + ar.y;  pr  += dq1(pr);  pr  += dq2(pr);          \
        float pz  = az.x + az.y;  pz  += dq1(pz);  pz  += dq2(pz);          \
        float pxn = an.x + an.y;  pxn += dq1(pxn); pxn += dq2(pxn);         \
        float phn = hn.x + hn.y;  phn += dq1(phn); phn += dq2(phn);         \
        float rg = FAST_RCP(1.0f + __builtin_exp2f(pr));                    \
        float zg = FAST_RCP(1.0f + __builtin_exp2f(pz));                    \
        float yy = fmaf(rg, phn, pxn);                                      \
        float ng = fmaf(-2.0f, FAST_RCP(1.0f + __builtin_exp2f(yy)), 1.0f); \
        h_own = fmaf(zg, h_own - ng, ng);                                   \
        float b0 = bperm(ba[0], h_own), b1 = bperm(ba[1], h_own);           \
        float b2 = bperm(ba[2], h_own), b3 = bperm(ba[3], h_own);           \
        hb2[0].x = b0; hb2[0].y = b1; hb2[1].x = b2; hb2[1].y = b3;         \
    } while (0)

    v2f hb2[2];
    hb2[0].x = 0.0f; hb2[0].y = 0.0f; hb2[1].x = 0.0f; hb2[1].y = 0.0f;
    float h_own = 0.0f;

    const int nch = (len + 7) >> 3;

    // prologue: 3 chunks (24 steps) in flight
    STAGE(0); STAGE(1); STAGE(2);

    for (int c = 0; c < nch; ++c) {
        // chunk c complete when <=8 staging loads outstanding (chunks c+1, c+2)
        asm volatile("s_waitcnt vmcnt(8)" ::: "memory");
        STAGE(c + 3);
        const float* cw = ldsr + ((c & 3) << 8);
        const int nst = min(8, len - (c << 3));
#pragma unroll
        for (int s = 0; s < 8; ++s) {
            if (s >= nst) break;
            STEP(cw, s);
        }
    }
    // final h of this row is h_own (replicated across the quad)

    // ---- FC head (redundant across lanes; once per row) ----
    float hv[16];
#pragma unroll
    for (int k = 0; k < 16; ++k) hv[k] = __shfl(h_own, 4 * k, 64);

    float e1 = fc1b[j];
#pragma unroll
    for (int k = 0; k < 16; ++k) e1 = fmaf(fc1w[j * HID + k], hv[k], e1);

    float v1[16];
#pragma unroll
    for (int k = 0; k < 16; ++k) v1[k] = fmaxf(__shfl(e1, 4 * k, 64), 0.0f);

    float e2 = fc2b[j];
#pragma unroll
    for (int k = 0; k < 16; ++k) e2 = fmaf(fc2w[j * HID + k], v1[k], e2);

    float v2a[16];
#pragma unroll
    for (int k = 0; k < 16; ++k) v2a[k] = fmaxf(__shfl(e2, 4 * k, 64), 0.0f);

    float e3 = fc3b[j];
#pragma unroll
    for (int k = 0; k < 16; ++k) e3 = fmaf(fc3w[j * HID + k], v2a[k], e3);

    if (q == 0) out[(size_t)row * HID + j] = e3;
}

extern "C" void kernel_launch(void* const* d_in, const int* in_sizes, int n_in,
                              void* d_out, int out_size, void* d_ws, size_t ws_size,
                              hipStream_t stream) {
    const float* x    = (const float*)d_in[0];
    const int*   lens = (const int*)d_in[1];
    const float* w_ih = (const float*)d_in[2];
    const float* w_hh = (const float*)d_in[3];
    const float* b_ih = (const float*)d_in[4];
    const float* b_hh = (const float*)d_in[5];
    const float* fc1w = (const float*)d_in[6];
    const float* fc1b = (const float*)d_in[7];
    const float* fc2w = (const float*)d_in[8];
    const float* fc2b = (const float*)d_in[9];
    const float* fc3w = (const float*)d_in[10];
    const float* fc3b = (const float*)d_in[11];
    float* out = (float*)d_out;

    const int B = in_sizes[1];
    const int T = (int)(in_sizes[0] / ((size_t)B * IN));

    // ws layout (ints): perm[B] | hist[512] | off[512]
    int* wsI = (int*)d_ws;
    const size_t need = ((size_t)B + 1024) * sizeof(int);
    const bool dosort = (ws_size >= need) && (T <= 512) && (T >= 8);
    int* perm = dosort ? wsI : nullptr;
    int* hist = wsI + B;
    int* off  = wsI + B + 512;

    if (dosort) {
        hipMemsetAsync(hist, 0, 512 * sizeof(int), stream);
        k_hist<<<(B + 255) / 256, 256, 0, stream>>>(lens, hist, B, T);
        k_scan<<<1, 512, 0, stream>>>(hist, off);
        k_scatter<<<(B + 255) / 256, 256, 0, stream>>>(lens, off, perm, B, T);
    }

    const int nblk = (B + 7) / 8;   // 8 rows (waves) per 512-thread block
    gru_enc_kernel<<<nblk, 512, 0, stream>>>(x, lens, w_ih, w_hh, b_ih, b_hh,
                                             fc1w, fc1b, fc2w, fc2b, fc3w, fc3b,
                                             out, perm, B, T, nblk);
}